// Round 1
// baseline (695.367 us; speedup 1.0000x reference)
//
#include <hip/hip_runtime.h>
#include <math.h>

#define N_NODES 20000
#define EMB 128
#define HID 64
#define RELS 8
#define CLS 16
#define HEADS 3
#define N_EDGES 640000
#define NEG 0.2f

// ---------------- CSR build ----------------
__global__ __launch_bounds__(256) void k_count(const int* __restrict__ dst, int* __restrict__ counts) {
    int e = blockIdx.x * blockDim.x + threadIdx.x;
    if (e < N_EDGES) atomicAdd(&counts[dst[e]], 1);
}

// single-block exclusive scan over 20000 counts
__global__ __launch_bounds__(256) void k_scan(const int* __restrict__ counts, int* __restrict__ offsets,
                                              int* __restrict__ cursor) {
    __shared__ int part[256];
    const int tid = threadIdx.x;
    const int CH = (N_NODES + 255) / 256;  // 79
    int base = tid * CH;
    int s = 0;
    for (int i = 0; i < CH; i++) {
        int idx = base + i;
        if (idx < N_NODES) s += counts[idx];
    }
    part[tid] = s;
    __syncthreads();
    for (int off = 1; off < 256; off <<= 1) {
        int v = (tid >= off) ? part[tid - off] : 0;
        __syncthreads();
        part[tid] += v;
        __syncthreads();
    }
    int run = (tid == 0) ? 0 : part[tid - 1];
    for (int i = 0; i < CH; i++) {
        int idx = base + i;
        if (idx < N_NODES) {
            offsets[idx] = run;
            cursor[idx] = run;
            run += counts[idx];
        }
    }
    if (tid == 255) offsets[N_NODES] = run;
}

__global__ __launch_bounds__(256) void k_scatter(const int* __restrict__ dst, int* __restrict__ cursor,
                                                 int* __restrict__ sorted) {
    int e = blockIdx.x * blockDim.x + threadIdx.x;
    if (e < N_EDGES) {
        int p = atomicAdd(&cursor[dst[e]], 1);
        sorted[p] = e;
    }
}

// ---------------- per-relation GEMM: xr[r] = x @ w[r] ----------------
// x: [N_NODES, K] row-major; w: [RELS, K, O]; xr: [RELS, N_NODES, O]
template <int K, int O>
__global__ __launch_bounds__(256) void k_gemm(const float* __restrict__ x, const float* __restrict__ w,
                                              float* __restrict__ xr) {
    const int r = blockIdx.z;
    const int m0 = blockIdx.x * 64;
    const int n0 = blockIdx.y * 64;
    const float* wr = w + (size_t)r * K * O;
    float* out = xr + (size_t)r * N_NODES * O;

    __shared__ float As[16][68];  // [kk][row], padded
    __shared__ float Bs[16][64];  // [kk][col]

    const int tid = threadIdx.x;
    const int tx = tid & 15, ty = tid >> 4;

    float acc[4][4] = {};

    for (int k0 = 0; k0 < K; k0 += 16) {
        // load A tile 64x16 as float4 per thread
        {
            int row = tid >> 2, kq = (tid & 3) << 2;
            int gm = m0 + row;
            float4 v = make_float4(0.f, 0.f, 0.f, 0.f);
            if (gm < N_NODES) v = *(const float4*)&x[(size_t)gm * K + k0 + kq];
            As[kq + 0][row] = v.x;
            As[kq + 1][row] = v.y;
            As[kq + 2][row] = v.z;
            As[kq + 3][row] = v.w;
        }
        // load B tile 16x64 as float4 per thread
        {
            int kk = tid >> 4, cq = (tid & 15) << 2;
            int gn = n0 + cq;
            float4 v = make_float4(0.f, 0.f, 0.f, 0.f);
            if (gn + 3 < O) v = *(const float4*)&wr[(size_t)(k0 + kk) * O + gn];
            *(float4*)&Bs[kk][cq] = v;
        }
        __syncthreads();
#pragma unroll
        for (int kk = 0; kk < 16; kk++) {
            float4 av = *(const float4*)&As[kk][ty * 4];
            float4 bv = *(const float4*)&Bs[kk][tx * 4];
            float a[4] = {av.x, av.y, av.z, av.w};
            float b[4] = {bv.x, bv.y, bv.z, bv.w};
#pragma unroll
            for (int i = 0; i < 4; i++)
#pragma unroll
                for (int j = 0; j < 4; j++) acc[i][j] += a[i] * b[j];
        }
        __syncthreads();
    }
#pragma unroll
    for (int i = 0; i < 4; i++) {
        int gm = m0 + ty * 4 + i;
        if (gm >= N_NODES) continue;
#pragma unroll
        for (int j = 0; j < 4; j++) {
            int gn = n0 + tx * 4 + j;
            if (gn < O) out[(size_t)gm * O + gn] = acc[i][j];
        }
    }
}

// ---------------- qdot/kdot: per (r,n) row projections ----------------
// xr row [O] dotted with q[:,h], k[:,h]; q,k: [O, HEADS] row-major
template <int O>
__global__ __launch_bounds__(256) void k_qk(const float* __restrict__ xr, const float* __restrict__ q,
                                            const float* __restrict__ k, float* __restrict__ qd,
                                            float* __restrict__ kd) {
    int wid = blockIdx.x * 4 + (threadIdx.x >> 6);
    int lane = threadIdx.x & 63;
    const float* row = xr + (size_t)wid * O;
    float qs[3] = {0.f, 0.f, 0.f}, ks[3] = {0.f, 0.f, 0.f};
    for (int o = lane; o < O; o += 64) {
        float v = row[o];
#pragma unroll
        for (int h = 0; h < 3; h++) {
            qs[h] += v * q[o * 3 + h];
            ks[h] += v * k[o * 3 + h];
        }
    }
#pragma unroll
    for (int off = 32; off >= 1; off >>= 1) {
#pragma unroll
        for (int h = 0; h < 3; h++) {
            qs[h] += __shfl_down(qs[h], off);
            ks[h] += __shfl_down(ks[h], off);
        }
    }
    if (lane == 0) {
#pragma unroll
        for (int h = 0; h < 3; h++) {
            qd[(size_t)wid * 3 + h] = qs[h];
            kd[(size_t)wid * 3 + h] = ks[h];
        }
    }
}

// ---------------- per-edge attention logits ----------------
__global__ __launch_bounds__(256) void k_alpha(const int* __restrict__ src, const int* __restrict__ dst,
                                               const int* __restrict__ et, const float* __restrict__ qd,
                                               const float* __restrict__ kd, float* __restrict__ alpha) {
    int e = blockIdx.x * blockDim.x + threadIdx.x;
    if (e >= N_EDGES) return;
    int r = et[e], s = src[e], d = dst[e];
    size_t bi = ((size_t)r * N_NODES + d) * 3;
    size_t bj = ((size_t)r * N_NODES + s) * 3;
#pragma unroll
    for (int h = 0; h < 3; h++) {
        float a = qd[bi + h] + kd[bj + h];
        alpha[(size_t)e * 3 + h] = (a > 0.f) ? a : NEG * a;
    }
}

// ---------------- layer-1 aggregation: softmax + weighted sum + mean-head + bias + relu ----------------
__global__ __launch_bounds__(256) void k_aggr1(const int* __restrict__ offsets, const int* __restrict__ sorted,
                                               const int* __restrict__ src, const int* __restrict__ et,
                                               const float* __restrict__ alpha, const float* __restrict__ xr,
                                               const float* __restrict__ b, float* __restrict__ x2) {
    int node = blockIdx.x * 4 + (threadIdx.x >> 6);
    int lane = threadIdx.x & 63;
    int beg = offsets[node], end = offsets[node + 1];

    float m0 = -INFINITY, m1 = -INFINITY, m2 = -INFINITY;
    for (int i = beg + lane; i < end; i += 64) {
        int e = sorted[i];
        m0 = fmaxf(m0, alpha[(size_t)e * 3 + 0]);
        m1 = fmaxf(m1, alpha[(size_t)e * 3 + 1]);
        m2 = fmaxf(m2, alpha[(size_t)e * 3 + 2]);
    }
#pragma unroll
    for (int off = 32; off >= 1; off >>= 1) {
        m0 = fmaxf(m0, __shfl_xor(m0, off));
        m1 = fmaxf(m1, __shfl_xor(m1, off));
        m2 = fmaxf(m2, __shfl_xor(m2, off));
    }

    float acc0 = 0.f, acc1 = 0.f, acc2 = 0.f;
    float d0 = 0.f, d1 = 0.f, d2 = 0.f;
    for (int i = beg; i < end; i++) {
        int e = sorted[i];
        int s = src[e];
        int r = et[e];
        float e0 = expf(alpha[(size_t)e * 3 + 0] - m0);
        float e1 = expf(alpha[(size_t)e * 3 + 1] - m1);
        float e2 = expf(alpha[(size_t)e * 3 + 2] - m2);
        d0 += e0; d1 += e1; d2 += e2;
        const float* row = xr + ((size_t)r * N_NODES + s) * 192;
        acc0 += e0 * row[lane];
        acc1 += e1 * row[64 + lane];
        acc2 += e2 * row[128 + lane];
    }
    float v = acc0 / (d0 + 1e-16f) + acc1 / (d1 + 1e-16f) + acc2 / (d2 + 1e-16f);
    v = v * (1.f / 3.f) + b[lane];
    x2[(size_t)node * 64 + lane] = (v > 0.f) ? v : 0.f;  // fused relu
}

// ---------------- layer-2 aggregation + sigmoid ----------------
__global__ __launch_bounds__(256) void k_aggr2(const int* __restrict__ offsets, const int* __restrict__ sorted,
                                               const int* __restrict__ src, const int* __restrict__ et,
                                               const float* __restrict__ alpha, const float* __restrict__ xr,
                                               const float* __restrict__ b, float* __restrict__ out) {
    int node = blockIdx.x * 4 + (threadIdx.x >> 6);
    int lane = threadIdx.x & 63;
    int beg = offsets[node], end = offsets[node + 1];

    float m0 = -INFINITY, m1 = -INFINITY, m2 = -INFINITY;
    for (int i = beg + lane; i < end; i += 64) {
        int e = sorted[i];
        m0 = fmaxf(m0, alpha[(size_t)e * 3 + 0]);
        m1 = fmaxf(m1, alpha[(size_t)e * 3 + 1]);
        m2 = fmaxf(m2, alpha[(size_t)e * 3 + 2]);
    }
#pragma unroll
    for (int off = 32; off >= 1; off >>= 1) {
        m0 = fmaxf(m0, __shfl_xor(m0, off));
        m1 = fmaxf(m1, __shfl_xor(m1, off));
        m2 = fmaxf(m2, __shfl_xor(m2, off));
    }

    int h = lane >> 4;  // head for lanes 0..47
    float acc = 0.f;
    float d0 = 0.f, d1 = 0.f, d2 = 0.f;
    for (int i = beg; i < end; i++) {
        int e = sorted[i];
        int s = src[e];
        int r = et[e];
        float e0 = expf(alpha[(size_t)e * 3 + 0] - m0);
        float e1 = expf(alpha[(size_t)e * 3 + 1] - m1);
        float e2 = expf(alpha[(size_t)e * 3 + 2] - m2);
        d0 += e0; d1 += e1; d2 += e2;
        if (lane < 48) {
            const float* row = xr + ((size_t)r * N_NODES + s) * 48;
            float eh = (h == 0) ? e0 : ((h == 1) ? e1 : e2);
            acc += eh * row[lane];
        }
    }
    float dh = (h == 0) ? d0 : ((h == 1) ? d1 : d2);
    float val = (lane < 48) ? acc / (dh + 1e-16f) : 0.f;
    float v16 = __shfl(val, (lane & 15) + 16);
    float v32 = __shfl(val, (lane & 15) + 32);
    if (lane < 16) {
        float s3 = (val + v16 + v32) * (1.f / 3.f) + b[lane];
        out[(size_t)node * 16 + lane] = 1.f / (1.f + expf(-s3));
    }
}

extern "C" void kernel_launch(void* const* d_in, const int* in_sizes, int n_in, void* d_out, int out_size,
                              void* d_ws, size_t ws_size, hipStream_t stream) {
    const float* emb = (const float*)d_in[0];
    const float* w1 = (const float*)d_in[1];
    const float* q1 = (const float*)d_in[2];
    const float* k1 = (const float*)d_in[3];
    const float* b1 = (const float*)d_in[4];
    const float* w2 = (const float*)d_in[5];
    const float* q2 = (const float*)d_in[6];
    const float* k2 = (const float*)d_in[7];
    const float* b2 = (const float*)d_in[8];
    const int* eidx = (const int*)d_in[9];
    const int* etype = (const int*)d_in[10];
    const int* srcv = eidx;
    const int* dstv = eidx + N_EDGES;
    float* out = (float*)d_out;

    char* p = (char*)d_ws;
    auto alloc = [&](size_t bytes) -> void* {
        void* q = p;
        p += (bytes + 255) & ~(size_t)255;
        return q;
    };
    int* counts = (int*)alloc((size_t)N_NODES * 4);
    int* offsets = (int*)alloc((size_t)(N_NODES + 1) * 4);
    int* cursor = (int*)alloc((size_t)N_NODES * 4);
    int* sorted = (int*)alloc((size_t)N_EDGES * 4);
    float* xr = (float*)alloc((size_t)RELS * N_NODES * 192 * 4);  // reused for layer2 (48 cols)
    float* qd = (float*)alloc((size_t)RELS * N_NODES * 3 * 4);
    float* kd = (float*)alloc((size_t)RELS * N_NODES * 3 * 4);
    float* alpha = (float*)alloc((size_t)N_EDGES * 3 * 4);
    float* x2 = (float*)alloc((size_t)N_NODES * 64 * 4);

    // CSR by destination (shared by both layers)
    hipMemsetAsync(counts, 0, (size_t)N_NODES * 4, stream);
    k_count<<<(N_EDGES + 255) / 256, 256, 0, stream>>>(dstv, counts);
    k_scan<<<1, 256, 0, stream>>>(counts, offsets, cursor);
    k_scatter<<<(N_EDGES + 255) / 256, 256, 0, stream>>>(dstv, cursor, sorted);

    // ---- layer 1 ----
    k_gemm<EMB, HEADS * HID><<<dim3(313, 3, 8), 256, 0, stream>>>(emb, w1, xr);
    k_qk<HEADS * HID><<<(RELS * N_NODES) / 4, 256, 0, stream>>>(xr, q1, k1, qd, kd);
    k_alpha<<<(N_EDGES + 255) / 256, 256, 0, stream>>>(srcv, dstv, etype, qd, kd, alpha);
    k_aggr1<<<N_NODES / 4, 256, 0, stream>>>(offsets, sorted, srcv, etype, alpha, xr, b1, x2);

    // ---- layer 2 ----
    k_gemm<HID, HEADS * CLS><<<dim3(313, 1, 8), 256, 0, stream>>>(x2, w2, xr);
    k_qk<HEADS * CLS><<<(RELS * N_NODES) / 4, 256, 0, stream>>>(xr, q2, k2, qd, kd);
    k_alpha<<<(N_EDGES + 255) / 256, 256, 0, stream>>>(srcv, dstv, etype, qd, kd, alpha);
    k_aggr2<<<N_NODES / 4, 256, 0, stream>>>(offsets, sorted, srcv, etype, alpha, xr, b2, out);
}

// Round 2
// 491.599 us; speedup vs baseline: 1.4145x; 1.4145x over previous
//
#include <hip/hip_runtime.h>
#include <hip/hip_bf16.h>
#include <math.h>

#define N_NODES 20000
#define EMB 128
#define HID 64
#define RELS 8
#define CLS 16
#define HEADS 3
#define N_EDGES 640000
#define NEG 0.2f

typedef unsigned short ushort_t;

__device__ __forceinline__ float b2f(ushort_t u) {
    return __uint_as_float(((unsigned int)u) << 16);
}
__device__ __forceinline__ ushort_t f2b(float f) {
    __hip_bfloat16 h = __float2bfloat16(f);
    return *reinterpret_cast<ushort_t*>(&h);
}

// ---------------- f32 -> bf16 conversion (vectorized) ----------------
__global__ __launch_bounds__(256) void k_cvt(const float* __restrict__ in, ushort_t* __restrict__ outp, int n4) {
    int i = blockIdx.x * blockDim.x + threadIdx.x;
    if (i >= n4) return;
    float4 v = *(const float4*)&in[(size_t)i * 4];
    ushort4 o;
    o.x = f2b(v.x); o.y = f2b(v.y); o.z = f2b(v.z); o.w = f2b(v.w);
    *(ushort4*)&outp[(size_t)i * 4] = o;
}

// ---------------- CSR build ----------------
__global__ __launch_bounds__(256) void k_count(const int* __restrict__ dst, int* __restrict__ counts) {
    int e = blockIdx.x * blockDim.x + threadIdx.x;
    if (e < N_EDGES) atomicAdd(&counts[dst[e]], 1);
}

__global__ __launch_bounds__(256) void k_scan(const int* __restrict__ counts, int* __restrict__ offsets,
                                              int* __restrict__ cursor) {
    __shared__ int part[256];
    const int tid = threadIdx.x;
    const int CH = (N_NODES + 255) / 256;  // 79
    int base = tid * CH;
    int s = 0;
    for (int i = 0; i < CH; i++) {
        int idx = base + i;
        if (idx < N_NODES) s += counts[idx];
    }
    part[tid] = s;
    __syncthreads();
    for (int off = 1; off < 256; off <<= 1) {
        int v = (tid >= off) ? part[tid - off] : 0;
        __syncthreads();
        part[tid] += v;
        __syncthreads();
    }
    int run = (tid == 0) ? 0 : part[tid - 1];
    for (int i = 0; i < CH; i++) {
        int idx = base + i;
        if (idx < N_NODES) {
            offsets[idx] = run;
            cursor[idx] = run;
            run += counts[idx];
        }
    }
    if (tid == 255) offsets[N_NODES] = run;
}

// scatter edge ids + per-edge (rel*N + src) into CSR order
__global__ __launch_bounds__(256) void k_scatter(const int* __restrict__ src, const int* __restrict__ dst,
                                                 const int* __restrict__ et, int* __restrict__ cursor,
                                                 int* __restrict__ ealpha, int* __restrict__ basekd) {
    int e = blockIdx.x * blockDim.x + threadIdx.x;
    if (e < N_EDGES) {
        int p = atomicAdd(&cursor[dst[e]], 1);
        ealpha[p] = e;
        basekd[p] = et[e] * N_NODES + src[e];
    }
}

// ---------------- per-relation GEMM (bf16 in, f32 compute, bf16 out) ----------------
// A: [N_NODES, K] bf16; B: [RELS, K, O] bf16; out: [RELS, N_NODES, O] bf16
template <int K, int O>
__global__ __launch_bounds__(256) void k_gemm(const ushort_t* __restrict__ A, const ushort_t* __restrict__ B,
                                              ushort_t* __restrict__ xr) {
    const int r = blockIdx.z;
    const int m0 = blockIdx.x * 64;
    const int n0 = blockIdx.y * 64;
    const ushort_t* Br = B + (size_t)r * K * O;
    ushort_t* out = xr + (size_t)r * N_NODES * O;

    __shared__ float As[16][68];
    __shared__ float Bs[16][64];

    const int tid = threadIdx.x;
    const int tx = tid & 15, ty = tid >> 4;

    float acc[4][4] = {};

    for (int k0 = 0; k0 < K; k0 += 16) {
        {
            int row = tid >> 2, kq = (tid & 3) << 2;
            int gm = m0 + row;
            ushort4 v = make_ushort4(0, 0, 0, 0);
            if (gm < N_NODES) v = *(const ushort4*)&A[(size_t)gm * K + k0 + kq];
            As[kq + 0][row] = b2f(v.x);
            As[kq + 1][row] = b2f(v.y);
            As[kq + 2][row] = b2f(v.z);
            As[kq + 3][row] = b2f(v.w);
        }
        {
            int kk = tid >> 4, cq = (tid & 15) << 2;
            int gn = n0 + cq;
            ushort4 v = make_ushort4(0, 0, 0, 0);
            if (gn + 3 < O) v = *(const ushort4*)&Br[(size_t)(k0 + kk) * O + gn];
            Bs[kk][cq + 0] = b2f(v.x);
            Bs[kk][cq + 1] = b2f(v.y);
            Bs[kk][cq + 2] = b2f(v.z);
            Bs[kk][cq + 3] = b2f(v.w);
        }
        __syncthreads();
#pragma unroll
        for (int kk = 0; kk < 16; kk++) {
            float4 av = *(const float4*)&As[kk][ty * 4];
            float4 bv = *(const float4*)&Bs[kk][tx * 4];
            float a[4] = {av.x, av.y, av.z, av.w};
            float b[4] = {bv.x, bv.y, bv.z, bv.w};
#pragma unroll
            for (int i = 0; i < 4; i++)
#pragma unroll
                for (int j = 0; j < 4; j++) acc[i][j] += a[i] * b[j];
        }
        __syncthreads();
    }
#pragma unroll
    for (int i = 0; i < 4; i++) {
        int gm = m0 + ty * 4 + i;
        int gn = n0 + tx * 4;
        if (gm < N_NODES && gn + 3 < O) {
            ushort4 o;
            o.x = f2b(acc[i][0]);
            o.y = f2b(acc[i][1]);
            o.z = f2b(acc[i][2]);
            o.w = f2b(acc[i][3]);
            *(ushort4*)&out[(size_t)gm * O + gn] = o;
        }
    }
}

// ---------------- qdot/kdot projections (bf16 rows) ----------------
template <int O>
__global__ __launch_bounds__(256) void k_qk(const ushort_t* __restrict__ xr, const float* __restrict__ q,
                                            const float* __restrict__ k, float* __restrict__ qd,
                                            float* __restrict__ kd) {
    int wid = blockIdx.x * 4 + (threadIdx.x >> 6);
    int lane = threadIdx.x & 63;
    const ushort_t* row = xr + (size_t)wid * O;
    float qs0 = 0.f, qs1 = 0.f, qs2 = 0.f, ks0 = 0.f, ks1 = 0.f, ks2 = 0.f;
    for (int o = lane; o < O; o += 64) {
        float v = b2f(row[o]);
        qs0 += v * q[o * 3 + 0];
        qs1 += v * q[o * 3 + 1];
        qs2 += v * q[o * 3 + 2];
        ks0 += v * k[o * 3 + 0];
        ks1 += v * k[o * 3 + 1];
        ks2 += v * k[o * 3 + 2];
    }
#pragma unroll
    for (int off = 32; off >= 1; off >>= 1) {
        qs0 += __shfl_down(qs0, off);
        qs1 += __shfl_down(qs1, off);
        qs2 += __shfl_down(qs2, off);
        ks0 += __shfl_down(ks0, off);
        ks1 += __shfl_down(ks1, off);
        ks2 += __shfl_down(ks2, off);
    }
    if (lane == 0) {
        qd[(size_t)wid * 3 + 0] = qs0;
        qd[(size_t)wid * 3 + 1] = qs1;
        qd[(size_t)wid * 3 + 2] = qs2;
        kd[(size_t)wid * 3 + 0] = ks0;
        kd[(size_t)wid * 3 + 1] = ks1;
        kd[(size_t)wid * 3 + 2] = ks2;
    }
}

// ---------------- per-edge attention logits (edge-original order) ----------------
__global__ __launch_bounds__(256) void k_alpha(const int* __restrict__ src, const int* __restrict__ dst,
                                               const int* __restrict__ et, const float* __restrict__ qd,
                                               const float* __restrict__ kd, float* __restrict__ alpha) {
    int e = blockIdx.x * blockDim.x + threadIdx.x;
    if (e >= N_EDGES) return;
    int r = et[e], s = src[e], d = dst[e];
    size_t bi = ((size_t)r * N_NODES + d) * 3;
    size_t bj = ((size_t)r * N_NODES + s) * 3;
#pragma unroll
    for (int h = 0; h < 3; h++) {
        float a = qd[bi + h] + kd[bj + h];
        alpha[(size_t)e * 3 + h] = (a > 0.f) ? a : NEG * a;
    }
}

// ---------------- per-node softmax stats -> normalized weights in CSR order ----------------
// w[i,h] = exp(alpha - max) / (denom + 1e-16) / 3   (head-mean folded in)
__global__ __launch_bounds__(256) void k_stats(const int* __restrict__ offsets, const int* __restrict__ ealpha,
                                               const float* __restrict__ alpha, float* __restrict__ wcsr) {
    int node = blockIdx.x * 4 + (threadIdx.x >> 6);
    int lane = threadIdx.x & 63;
    int beg = offsets[node], end = offsets[node + 1];
    int deg = end - beg;

    if (deg <= 64) {
        float a0 = -INFINITY, a1 = -INFINITY, a2 = -INFINITY;
        if (lane < deg) {
            int e = ealpha[beg + lane];
            a0 = alpha[(size_t)e * 3 + 0];
            a1 = alpha[(size_t)e * 3 + 1];
            a2 = alpha[(size_t)e * 3 + 2];
        }
        float m0 = a0, m1 = a1, m2 = a2;
#pragma unroll
        for (int off = 32; off >= 1; off >>= 1) {
            m0 = fmaxf(m0, __shfl_xor(m0, off));
            m1 = fmaxf(m1, __shfl_xor(m1, off));
            m2 = fmaxf(m2, __shfl_xor(m2, off));
        }
        float e0 = 0.f, e1 = 0.f, e2 = 0.f;
        if (lane < deg) {
            e0 = expf(a0 - m0);
            e1 = expf(a1 - m1);
            e2 = expf(a2 - m2);
        }
        float s0 = e0, s1 = e1, s2 = e2;
#pragma unroll
        for (int off = 32; off >= 1; off >>= 1) {
            s0 += __shfl_xor(s0, off);
            s1 += __shfl_xor(s1, off);
            s2 += __shfl_xor(s2, off);
        }
        float i0 = 1.f / (3.f * (s0 + 1e-16f));
        float i1 = 1.f / (3.f * (s1 + 1e-16f));
        float i2 = 1.f / (3.f * (s2 + 1e-16f));
        if (lane < deg) {
            size_t p = (size_t)(beg + lane) * 3;
            wcsr[p + 0] = e0 * i0;
            wcsr[p + 1] = e1 * i1;
            wcsr[p + 2] = e2 * i2;
        }
    } else {
        float m0 = -INFINITY, m1 = -INFINITY, m2 = -INFINITY;
        for (int i = beg + lane; i < end; i += 64) {
            int e = ealpha[i];
            m0 = fmaxf(m0, alpha[(size_t)e * 3 + 0]);
            m1 = fmaxf(m1, alpha[(size_t)e * 3 + 1]);
            m2 = fmaxf(m2, alpha[(size_t)e * 3 + 2]);
        }
#pragma unroll
        for (int off = 32; off >= 1; off >>= 1) {
            m0 = fmaxf(m0, __shfl_xor(m0, off));
            m1 = fmaxf(m1, __shfl_xor(m1, off));
            m2 = fmaxf(m2, __shfl_xor(m2, off));
        }
        float s0 = 0.f, s1 = 0.f, s2 = 0.f;
        for (int i = beg + lane; i < end; i += 64) {
            int e = ealpha[i];
            s0 += expf(alpha[(size_t)e * 3 + 0] - m0);
            s1 += expf(alpha[(size_t)e * 3 + 1] - m1);
            s2 += expf(alpha[(size_t)e * 3 + 2] - m2);
        }
#pragma unroll
        for (int off = 32; off >= 1; off >>= 1) {
            s0 += __shfl_xor(s0, off);
            s1 += __shfl_xor(s1, off);
            s2 += __shfl_xor(s2, off);
        }
        float i0 = 1.f / (3.f * (s0 + 1e-16f));
        float i1 = 1.f / (3.f * (s1 + 1e-16f));
        float i2 = 1.f / (3.f * (s2 + 1e-16f));
        for (int i = beg + lane; i < end; i += 64) {
            int e = ealpha[i];
            wcsr[(size_t)i * 3 + 0] = expf(alpha[(size_t)e * 3 + 0] - m0) * i0;
            wcsr[(size_t)i * 3 + 1] = expf(alpha[(size_t)e * 3 + 1] - m1) * i1;
            wcsr[(size_t)i * 3 + 2] = expf(alpha[(size_t)e * 3 + 2] - m2) * i2;
        }
    }
}

// ---------------- layer-1 aggregation: weighted gather-sum + bias + relu -> bf16 ----------------
__global__ __launch_bounds__(256) void k_aggr1(const int* __restrict__ offsets, const int* __restrict__ basekd,
                                               const float* __restrict__ wcsr, const ushort_t* __restrict__ xr,
                                               const float* __restrict__ bias, ushort_t* __restrict__ x2) {
    int node = blockIdx.x * 4 + (threadIdx.x >> 6);
    int lane = threadIdx.x & 63;
    int beg = offsets[node], end = offsets[node + 1];

    float acc0 = 0.f, acc1 = 0.f, acc2 = 0.f;
    int i = beg;
    for (; i + 4 <= end; i += 4) {
        int ba = basekd[i], bb = basekd[i + 1], bc = basekd[i + 2], bd = basekd[i + 3];
        const ushort_t* ra = xr + (size_t)ba * 192;
        const ushort_t* rb = xr + (size_t)bb * 192;
        const ushort_t* rc = xr + (size_t)bc * 192;
        const ushort_t* rd = xr + (size_t)bd * 192;
        const float* wp = wcsr + (size_t)i * 3;
        float wa0 = wp[0], wa1 = wp[1], wa2 = wp[2];
        float wb0 = wp[3], wb1 = wp[4], wb2 = wp[5];
        float wc0 = wp[6], wc1 = wp[7], wc2 = wp[8];
        float wd0 = wp[9], wd1 = wp[10], wd2 = wp[11];
        ushort_t ua0 = ra[lane], ua1 = ra[64 + lane], ua2 = ra[128 + lane];
        ushort_t ub0 = rb[lane], ub1 = rb[64 + lane], ub2 = rb[128 + lane];
        ushort_t uc0 = rc[lane], uc1 = rc[64 + lane], uc2 = rc[128 + lane];
        ushort_t ud0 = rd[lane], ud1 = rd[64 + lane], ud2 = rd[128 + lane];
        acc0 += wa0 * b2f(ua0) + wb0 * b2f(ub0) + wc0 * b2f(uc0) + wd0 * b2f(ud0);
        acc1 += wa1 * b2f(ua1) + wb1 * b2f(ub1) + wc1 * b2f(uc1) + wd1 * b2f(ud1);
        acc2 += wa2 * b2f(ua2) + wb2 * b2f(ub2) + wc2 * b2f(uc2) + wd2 * b2f(ud2);
    }
    for (; i < end; i++) {
        int ba = basekd[i];
        const ushort_t* ra = xr + (size_t)ba * 192;
        const float* wp = wcsr + (size_t)i * 3;
        acc0 += wp[0] * b2f(ra[lane]);
        acc1 += wp[1] * b2f(ra[64 + lane]);
        acc2 += wp[2] * b2f(ra[128 + lane]);
    }
    float v = acc0 + acc1 + acc2 + bias[lane];
    x2[(size_t)node * 64 + lane] = f2b(v > 0.f ? v : 0.f);
}

// ---------------- layer-2 aggregation + sigmoid (4 edge-groups x 16 classes) ----------------
__global__ __launch_bounds__(256) void k_aggr2(const int* __restrict__ offsets, const int* __restrict__ basekd,
                                               const float* __restrict__ wcsr, const ushort_t* __restrict__ xr,
                                               const float* __restrict__ bias, float* __restrict__ outp) {
    int node = blockIdx.x * 4 + (threadIdx.x >> 6);
    int lane = threadIdx.x & 63;
    int g = lane >> 4, c = lane & 15;
    int beg = offsets[node], end = offsets[node + 1];

    float acc = 0.f;
    int i = beg + g;
    for (; i + 4 < end; i += 8) {
        int ba = basekd[i], bb = basekd[i + 4];
        const ushort_t* ra = xr + (size_t)ba * 48;
        const ushort_t* rb = xr + (size_t)bb * 48;
        float wa0 = wcsr[(size_t)i * 3 + 0], wa1 = wcsr[(size_t)i * 3 + 1], wa2 = wcsr[(size_t)i * 3 + 2];
        float wb0 = wcsr[(size_t)(i + 4) * 3 + 0], wb1 = wcsr[(size_t)(i + 4) * 3 + 1],
              wb2 = wcsr[(size_t)(i + 4) * 3 + 2];
        ushort_t a0 = ra[c], a1 = ra[16 + c], a2 = ra[32 + c];
        ushort_t b0 = rb[c], b1 = rb[16 + c], b2 = rb[32 + c];
        acc += wa0 * b2f(a0) + wa1 * b2f(a1) + wa2 * b2f(a2);
        acc += wb0 * b2f(b0) + wb1 * b2f(b1) + wb2 * b2f(b2);
    }
    for (; i < end; i += 4) {
        int ba = basekd[i];
        const ushort_t* ra = xr + (size_t)ba * 48;
        float w0 = wcsr[(size_t)i * 3 + 0], w1 = wcsr[(size_t)i * 3 + 1], w2 = wcsr[(size_t)i * 3 + 2];
        acc += w0 * b2f(ra[c]) + w1 * b2f(ra[16 + c]) + w2 * b2f(ra[32 + c]);
    }
    acc += __shfl_xor(acc, 16);
    acc += __shfl_xor(acc, 32);
    if (lane < 16) {
        float s = acc + bias[lane];
        outp[(size_t)node * 16 + lane] = 1.f / (1.f + expf(-s));
    }
}

extern "C" void kernel_launch(void* const* d_in, const int* in_sizes, int n_in, void* d_out, int out_size,
                              void* d_ws, size_t ws_size, hipStream_t stream) {
    const float* emb = (const float*)d_in[0];
    const float* w1 = (const float*)d_in[1];
    const float* q1 = (const float*)d_in[2];
    const float* k1 = (const float*)d_in[3];
    const float* b1 = (const float*)d_in[4];
    const float* w2 = (const float*)d_in[5];
    const float* q2 = (const float*)d_in[6];
    const float* k2 = (const float*)d_in[7];
    const float* b2 = (const float*)d_in[8];
    const int* eidx = (const int*)d_in[9];
    const int* etype = (const int*)d_in[10];
    const int* srcv = eidx;
    const int* dstv = eidx + N_EDGES;
    float* out = (float*)d_out;

    char* p = (char*)d_ws;
    auto alloc = [&](size_t bytes) -> void* {
        void* q = p;
        p += (bytes + 255) & ~(size_t)255;
        return q;
    };
    int* counts = (int*)alloc((size_t)N_NODES * 4);
    int* offsets = (int*)alloc((size_t)(N_NODES + 1) * 4);
    int* cursor = (int*)alloc((size_t)N_NODES * 4);
    int* ealpha = (int*)alloc((size_t)N_EDGES * 4);
    int* basekd = (int*)alloc((size_t)N_EDGES * 4);
    ushort_t* emb_b = (ushort_t*)alloc((size_t)N_NODES * EMB * 2);
    ushort_t* w1_b = (ushort_t*)alloc((size_t)RELS * EMB * 192 * 2);
    ushort_t* w2_b = (ushort_t*)alloc((size_t)RELS * HID * 48 * 2);
    ushort_t* xr_b = (ushort_t*)alloc((size_t)RELS * N_NODES * 192 * 2);  // layer2 reuses (48 cols)
    float* qd = (float*)alloc((size_t)RELS * N_NODES * 3 * 4);
    float* kd = (float*)alloc((size_t)RELS * N_NODES * 3 * 4);
    float* alpha = (float*)alloc((size_t)N_EDGES * 3 * 4);
    float* wcsr = (float*)alloc((size_t)N_EDGES * 3 * 4);
    ushort_t* x2_b = (ushort_t*)alloc((size_t)N_NODES * HID * 2);

    // input conversions to bf16
    k_cvt<<<(N_NODES * EMB / 4 + 255) / 256, 256, 0, stream>>>(emb, emb_b, N_NODES * EMB / 4);
    k_cvt<<<(RELS * EMB * 192 / 4 + 255) / 256, 256, 0, stream>>>(w1, w1_b, RELS * EMB * 192 / 4);
    k_cvt<<<(RELS * HID * 48 / 4 + 255) / 256, 256, 0, stream>>>(w2, w2_b, RELS * HID * 48 / 4);

    // CSR by destination (shared by both layers)
    hipMemsetAsync(counts, 0, (size_t)N_NODES * 4, stream);
    k_count<<<(N_EDGES + 255) / 256, 256, 0, stream>>>(dstv, counts);
    k_scan<<<1, 256, 0, stream>>>(counts, offsets, cursor);
    k_scatter<<<(N_EDGES + 255) / 256, 256, 0, stream>>>(srcv, dstv, etype, cursor, ealpha, basekd);

    // ---- layer 1 ----
    k_gemm<EMB, 192><<<dim3(313, 3, 8), 256, 0, stream>>>(emb_b, w1_b, xr_b);
    k_qk<192><<<(RELS * N_NODES) / 4, 256, 0, stream>>>(xr_b, q1, k1, qd, kd);
    k_alpha<<<(N_EDGES + 255) / 256, 256, 0, stream>>>(srcv, dstv, etype, qd, kd, alpha);
    k_stats<<<N_NODES / 4, 256, 0, stream>>>(offsets, ealpha, alpha, wcsr);
    k_aggr1<<<N_NODES / 4, 256, 0, stream>>>(offsets, basekd, wcsr, xr_b, b1, x2_b);

    // ---- layer 2 ----
    k_gemm<HID, 48><<<dim3(313, 1, 8), 256, 0, stream>>>(x2_b, w2_b, xr_b);
    k_qk<48><<<(RELS * N_NODES) / 4, 256, 0, stream>>>(xr_b, q2, k2, qd, kd);
    k_alpha<<<(N_EDGES + 255) / 256, 256, 0, stream>>>(srcv, dstv, etype, qd, kd, alpha);
    k_stats<<<N_NODES / 4, 256, 0, stream>>>(offsets, ealpha, alpha, wcsr);
    k_aggr2<<<N_NODES / 4, 256, 0, stream>>>(offsets, basekd, wcsr, xr_b, b2, out);
}